// Round 7
// baseline (11880.482 us; speedup 1.0000x reference)
//
#include <hip/hip_runtime.h>
#include <hip/hip_bf16.h>

#define B   128
#define NA  8
#define AD  16
#define DM  512
#define DI  1024
#define DS  32
#define DC  4
#define DR  32
#define NB  4
#define OD  128
#define TPB 512

typedef __hip_bfloat16 bf16;
typedef unsigned int uint32;
typedef unsigned short ushort16;

__device__ __forceinline__ float bf2f(bf16 h){ return __bfloat162float(h); }
__device__ __forceinline__ float sigmoidf_(float x){ return 1.0f/(1.0f+__expf(-x)); }
__device__ __forceinline__ float softplusf_(float x){ return fmaxf(x,0.0f)+log1pf(__expf(-fabsf(x))); }
__device__ __forceinline__ float lo2f(uint32 u){ return __uint_as_float(u<<16); }
__device__ __forceinline__ float hi2f(uint32 u){ return __uint_as_float(u & 0xffff0000u); }
__device__ __forceinline__ float us2f(ushort16 u){ return __uint_as_float(((uint32)u)<<16); }
__device__ __forceinline__ uint32 packbf2(float a, float b){
    bf16 ha = __float2bfloat16(a), hb = __float2bfloat16(b);
    ushort16 sa = *reinterpret_cast<ushort16*>(&ha);
    ushort16 sb = *reinterpret_cast<ushort16*>(&hb);
    return (uint32)sa | ((uint32)sb << 16);
}
__device__ __forceinline__ ushort16 f2us(float a){
    bf16 ha = __float2bfloat16(a);
    return *reinterpret_cast<ushort16*>(&ha);
}

// ---------------- setup kernels ----------------

// negA[bs][d][s] = -exp(A_log), bs = nb*2+st
__global__ __launch_bounds__(256) void k_negA(const float* __restrict__ Als,
    const float* __restrict__ Alc, float* __restrict__ negA)
{
    int idx = blockIdx.x*256 + threadIdx.x;   // < 2*NB*DI*DS = 262144
    int bs = idx >> 15;
    int r  = idx & 32767;
    int nb = bs >> 1, st = bs & 1;
    const float* src = (st ? Alc : Als) + (size_t)nb*DI*DS + r;
    negA[idx] = -__expf(*src);
}

// ctx[i][b][m] = obs_rep[b][i][m] + obs[b][i] @ W_obs
__global__ __launch_bounds__(256) void k_ctx(const float* __restrict__ obs_rep,
    const float* __restrict__ obs, const float* __restrict__ Wobs,
    float* __restrict__ ctx)
{
    int ib = blockIdx.x;          // < B*8
    int b = ib >> 3, i = ib & 7;
    __shared__ float orow[OD];
    int tid = threadIdx.x;
    if (tid < OD) orow[tid] = obs[(size_t)(b*NA+i)*OD + tid];
    __syncthreads();
    for (int m = tid; m < DM; m += 256){
        float acc = obs_rep[(size_t)(b*NA+i)*DM + m];
        for (int o = 0; o < OD; o++)
            acc += orow[o]*Wobs[o*DM + m];
        ctx[(size_t)(i*B + b)*DM + m] = acc;
    }
}

// W1u[bs][k][p] = packed bf16 pair (cols 2p,2p+1) of in_proj[nb] (512 x 2048)
__global__ __launch_bounds__(256) void k_w1(const float* __restrict__ Ws,
    const float* __restrict__ Wc, uint32* __restrict__ W1u)
{
    int idx = blockIdx.x*256 + threadIdx.x;   // < 8*512*1024 = 4194304
    int bs = idx >> 19;
    int r  = idx & 524287;
    int k  = r >> 10, p = r & 1023;
    int nb = bs >> 1, st = bs & 1;
    const float* src = (st ? Wc : Ws) + (size_t)nb*DM*2*DI + (size_t)k*(2*DI) + 2*p;
    W1u[idx] = packbf2(src[0], src[1]);
}

// Wou[bs][k][p] = packed pair of out_proj[nb] (1024 x 512)
__global__ __launch_bounds__(256) void k_wo(const float* __restrict__ Ws,
    const float* __restrict__ Wc, uint32* __restrict__ Wou)
{
    int idx = blockIdx.x*256 + threadIdx.x;   // < 8*1024*256 = 2097152
    int bs = idx >> 18;
    int r  = idx & 262143;
    int k  = r >> 8, p = r & 255;
    int nb = bs >> 1, st = bs & 1;
    const float* src = (st ? Wc : Ws) + (size_t)nb*DI*DM + (size_t)k*DM + 2*p;
    Wou[idx] = packbf2(src[0], src[1]);
}

// Wxb[bs][k][j] bf16 of x_proj (1024 x 96)
__global__ __launch_bounds__(256) void k_wx(const float* __restrict__ Ws,
    const float* __restrict__ Wc, ushort16* __restrict__ Wxb)
{
    int idx = blockIdx.x*256 + threadIdx.x;   // < 8*98304 = 786432
    int bs = idx / 98304;
    int r  = idx % 98304;
    int nb = bs >> 1, st = bs & 1;
    const float* src = (st ? Wc : Ws) + (size_t)nb*DI*96 + r;
    Wxb[idx] = f2us(*src);
}

// Wdtb[bs][r][d] bf16 of dt_proj (32 x 1024)
__global__ __launch_bounds__(256) void k_wdt(const float* __restrict__ Ws,
    const float* __restrict__ Wc, ushort16* __restrict__ Wdtb)
{
    int idx = blockIdx.x*256 + threadIdx.x;   // < 8*32768 = 262144
    int bs = idx >> 15;
    int r  = idx & 32767;
    int nb = bs >> 1, st = bs & 1;
    const float* src = (st ? Wc : Ws) + (size_t)nb*DR*DI + r;
    Wdtb[idx] = f2us(*src);
}

// ---------------- persistent main kernel: one block per batch row ----------------

__global__ __launch_bounds__(TPB, 1) void k_main(
    const float* __restrict__ ln1, const float* __restrict__ ln2,
    const float* __restrict__ lno, const float* __restrict__ Whead,
    const float* __restrict__ logstd, const float* __restrict__ eps,
    const float* __restrict__ Wemb, const float* __restrict__ bemb,
    const float* __restrict__ cw_s, const float* __restrict__ cb_s,
    const float* __restrict__ dtb_s, const float* __restrict__ D_s,
    const float* __restrict__ cw_c, const float* __restrict__ cb_c,
    const float* __restrict__ dtb_c, const float* __restrict__ D_c,
    const uint32* __restrict__ W1u, const uint32* __restrict__ Wou,
    const ushort16* __restrict__ Wxb, const ushort16* __restrict__ Wdtb,
    const float* __restrict__ negA, const float* __restrict__ ctxG,
    uint32* __restrict__ hG, float* __restrict__ out)
{
    int b = blockIdx.x;
    int t = threadIdx.x;
    int lane = t & 63, wid = t >> 6;

    __shared__ float xls[DM];
    __shared__ float ulnL[DM];
    __shared__ float xcs[DI];
    __shared__ float szs[DI];
    __shared__ float yzs[DI];
    __shared__ float red[1024];
    __shared__ float part[384];
    __shared__ float rowS[96];
    __shared__ float wps[8], wpq[8], ms[2];
    __shared__ float actv[AD], lpterm[AD];
    __shared__ uint32 convrU[8][DC][512];   // per-stream conv ring, packed col-pairs (64 KB)

    xls[t] = bemb[t];
    __syncthreads();

    for (int i = 0; i < NA; i++){
        for (int nb = 0; nb < NB; nb++){
            for (int st = 0; st < 2; st++){
                int bs = nb*2 + st;
                // ---------- LN (+ctx) ----------
                {
                    float v = xls[t];
                    float s = v, q = v*v;
                    for (int off = 32; off > 0; off >>= 1){
                        s += __shfl_down(s, off);
                        q += __shfl_down(q, off);
                    }
                    if (lane == 0){ wps[wid] = s; wpq[wid] = q; }
                    __syncthreads();
                    if (t == 0){
                        float S = 0.f, Q = 0.f;
                        #pragma unroll
                        for (int w = 0; w < 8; w++){ S += wps[w]; Q += wpq[w]; }
                        float m = S*(1.0f/DM);
                        float var = Q*(1.0f/DM) - m*m;
                        ms[0] = m; ms[1] = rsqrtf(var + 1e-5f);
                    }
                    __syncthreads();
                    const float* g = (st ? ln2 : ln1) + nb*DM;
                    float u = (v - ms[0])*ms[1]*g[t];
                    if (st) u += ctxG[((size_t)i*B + b)*DM + t];
                    ulnL[t] = u;
                }
                __syncthreads();
                // ---------- gemm1: xz = uln @ Win ----------
                {
                    const uint32* w1 = W1u + ((size_t)bs << 19);
                    float a00 = 0.f, a01 = 0.f, a10 = 0.f, a11 = 0.f;
                    for (int k = 0; k < DM; k += 4){
                        float4 a4 = *(const float4*)&ulnL[k];
                        const uint32* wk = w1 + (size_t)k*1024;
                        uint32 u0, u1;
                        u0 = wk[t];        u1 = wk[t+512];
                        a00 += a4.x*lo2f(u0); a01 += a4.x*hi2f(u0);
                        a10 += a4.x*lo2f(u1); a11 += a4.x*hi2f(u1);
                        u0 = wk[1024 + t]; u1 = wk[1024 + t+512];
                        a00 += a4.y*lo2f(u0); a01 += a4.y*hi2f(u0);
                        a10 += a4.y*lo2f(u1); a11 += a4.y*hi2f(u1);
                        u0 = wk[2048 + t]; u1 = wk[2048 + t+512];
                        a00 += a4.z*lo2f(u0); a01 += a4.z*hi2f(u0);
                        a10 += a4.z*lo2f(u1); a11 += a4.z*hi2f(u1);
                        u0 = wk[3072 + t]; u1 = wk[3072 + t+512];
                        a00 += a4.w*lo2f(u0); a01 += a4.w*hi2f(u0);
                        a10 += a4.w*lo2f(u1); a11 += a4.w*hi2f(u1);
                    }
                    // epilogue: x-part cols d0=2t,2t+1 -> conv ring + silu -> xc
                    const float* cw = (st ? cw_c : cw_s) + nb*DC*DI;
                    const float* cb = (st ? cb_c : cb_s) + nb*DI;
                    int d0 = 2*t;
                    int slot = i & 3;
                    convrU[bs][slot][t] = packbf2(a00, a01);
                    float s0 = cb[d0]   + cw[3*DI + d0]*a00;
                    float s1 = cb[d0+1] + cw[3*DI + d0+1]*a01;
                    if (i >= 1){ uint32 u = convrU[bs][(i-1)&3][t];
                        s0 += cw[2*DI + d0]*lo2f(u); s1 += cw[2*DI + d0+1]*hi2f(u); }
                    if (i >= 2){ uint32 u = convrU[bs][(i-2)&3][t];
                        s0 += cw[1*DI + d0]*lo2f(u); s1 += cw[1*DI + d0+1]*hi2f(u); }
                    if (i >= 3){ uint32 u = convrU[bs][(i-3)&3][t];
                        s0 += cw[0*DI + d0]*lo2f(u); s1 += cw[0*DI + d0+1]*hi2f(u); }
                    xcs[d0]   = s0*sigmoidf_(s0);
                    xcs[d0+1] = s1*sigmoidf_(s1);
                    // z-part cols 1024+2t,1025+2t -> silu -> sz
                    szs[d0]   = a10*sigmoidf_(a10);
                    szs[d0+1] = a11*sigmoidf_(a11);
                }
                __syncthreads();
                // ---------- xproj: row[96] = xc @ Wx ----------
                if (t < 384){
                    int col = t % 96, sl = t / 96;
                    const ushort16* wx = Wxb + (size_t)bs*98304;
                    float acc = 0.f;
                    int k0 = sl*256;
                    #pragma unroll 4
                    for (int k = k0; k < k0 + 256; k++)
                        acc += xcs[k]*us2f(wx[(size_t)k*96 + col]);
                    part[t] = acc;
                }
                __syncthreads();
                if (t < 96) rowS[t] = part[t] + part[t+96] + part[t+192] + part[t+288];
                __syncthreads();
                // ---------- dt + h update + y ----------
                {
                    const ushort16* wdt = Wdtb + ((size_t)bs << 15);
                    const float* dtbp = (st ? dtb_c : dtb_s) + nb*DI;
                    const float* Dp   = (st ? D_c   : D_s  ) + nb*DI;
                    const float* naB  = negA + ((size_t)bs << 15);
                    uint32* hB = hG + (((size_t)bs*B + b) << 14);
                    #pragma unroll
                    for (int e = 0; e < 2; e++){
                        int d = t + e*512;
                        float dp = dtbp[d];
                        #pragma unroll 8
                        for (int r = 0; r < DR; r++)
                            dp += rowS[r]*us2f(wdt[(size_t)r*DI + d]);
                        float delta = softplusf_(dp);
                        float xcv = xcs[d];
                        float dxc = delta*xcv;
                        const float4* nap = (const float4*)(naB + (size_t)d*DS);
                        uint4* hp = (uint4*)(hB + (size_t)d*16);
                        float y = 0.f;
                        #pragma unroll
                        for (int q = 0; q < 4; q++){
                            uint4 hu = (i == 0) ? make_uint4(0u,0u,0u,0u) : hp[q];
                            float4 na0 = nap[2*q], na1 = nap[2*q+1];
                            int s0 = 8*q;
                            float h0 = lo2f(hu.x), h1 = hi2f(hu.x);
                            float h2 = lo2f(hu.y), h3 = hi2f(hu.y);
                            float h4 = lo2f(hu.z), h5 = hi2f(hu.z);
                            float h6 = lo2f(hu.w), h7 = hi2f(hu.w);
                            h0 = __expf(delta*na0.x)*h0 + dxc*rowS[DR+s0+0];
                            h1 = __expf(delta*na0.y)*h1 + dxc*rowS[DR+s0+1];
                            h2 = __expf(delta*na0.z)*h2 + dxc*rowS[DR+s0+2];
                            h3 = __expf(delta*na0.w)*h3 + dxc*rowS[DR+s0+3];
                            h4 = __expf(delta*na1.x)*h4 + dxc*rowS[DR+s0+4];
                            h5 = __expf(delta*na1.y)*h5 + dxc*rowS[DR+s0+5];
                            h6 = __expf(delta*na1.z)*h6 + dxc*rowS[DR+s0+6];
                            h7 = __expf(delta*na1.w)*h7 + dxc*rowS[DR+s0+7];
                            y += h0*rowS[DR+DS+s0+0] + h1*rowS[DR+DS+s0+1]
                               + h2*rowS[DR+DS+s0+2] + h3*rowS[DR+DS+s0+3]
                               + h4*rowS[DR+DS+s0+4] + h5*rowS[DR+DS+s0+5]
                               + h6*rowS[DR+DS+s0+6] + h7*rowS[DR+DS+s0+7];
                            hu.x = packbf2(h0,h1); hu.y = packbf2(h2,h3);
                            hu.z = packbf2(h4,h5); hu.w = packbf2(h6,h7);
                            hp[q] = hu;
                        }
                        y += Dp[d]*xcv;
                        yzs[d] = y*szs[d];
                    }
                }
                __syncthreads();
                // ---------- gemm2: x += yz @ Wout ----------
                {
                    int pair = t & 255, kh = t >> 8;
                    const uint32* wo = Wou + ((size_t)bs << 18);
                    float a0 = 0.f, a1 = 0.f;
                    int kbeg = kh*512;
                    for (int k = kbeg; k < kbeg + 512; k += 4){
                        float4 a4 = *(const float4*)&yzs[k];
                        const uint32* wk = wo + (size_t)k*256 + pair;
                        uint32 u;
                        u = wk[0];   a0 += a4.x*lo2f(u); a1 += a4.x*hi2f(u);
                        u = wk[256]; a0 += a4.y*lo2f(u); a1 += a4.y*hi2f(u);
                        u = wk[512]; a0 += a4.z*lo2f(u); a1 += a4.z*hi2f(u);
                        u = wk[768]; a0 += a4.w*lo2f(u); a1 += a4.w*hi2f(u);
                    }
                    red[t] = a0; red[512 + t] = a1;
                    __syncthreads();
                    if (t < 256){
                        xls[2*t]   += red[t]       + red[t + 256];
                        xls[2*t+1] += red[512 + t] + red[512 + t + 256];
                    }
                }
                __syncthreads();
            }
        }
        // ---------- head ----------
        {
            float v = xls[t];
            float s = v, q = v*v;
            for (int off = 32; off > 0; off >>= 1){
                s += __shfl_down(s, off);
                q += __shfl_down(q, off);
            }
            if (lane == 0){ wps[wid] = s; wpq[wid] = q; }
            __syncthreads();
            if (t == 0){
                float S = 0.f, Q = 0.f;
                #pragma unroll
                for (int w = 0; w < 8; w++){ S += wps[w]; Q += wpq[w]; }
                float m = S*(1.0f/DM);
                float var = Q*(1.0f/DM) - m*m;
                ms[0] = m; ms[1] = rsqrtf(var + 1e-5f);
            }
            __syncthreads();
            ulnL[t] = (v - ms[0])*ms[1]*lno[t];
            __syncthreads();
            // mean[16] = uln @ Whead, split-K 32 slices of 16
            {
                int j = t & 15, ks = t >> 4;
                float acc = 0.f;
                int k0 = ks*16;
                #pragma unroll
                for (int k = k0; k < k0 + 16; k++)
                    acc += ulnL[k]*Whead[k*AD + j];
                red[t] = acc;
            }
            __syncthreads();
            if (t < AD){
                int j = t;
                float mean = 0.f;
                #pragma unroll
                for (int ks = 0; ks < 32; ks++) mean += red[ks*16 + j];
                float stdj = softplusf_(logstd[j]);
                float e = eps[((size_t)b*NA + i)*AD + j];
                float raw = mean + stdj*e;
                float act = tanhf(raw);
                out[((size_t)b*NA + i)*AD + j] = act;                                    // acts
                out[(size_t)NA*B*AD + (size_t)B*NA + ((size_t)b*NA + i)*AD + j] = raw;   // raws
                actv[j] = act;
                lpterm[j] = -0.5f*e*e - logf(stdj)
                            - 2.0f*(0.69314718f - raw - softplusf_(-2.0f*raw));
            }
            __syncthreads();
            if (t == 0){
                float lp = 0.f;
                #pragma unroll
                for (int j = 0; j < AD; j++) lp += lpterm[j];
                lp -= 0.5f*AD*1.8378770664f;
                out[(size_t)NA*B*AD + (size_t)b*NA + i] = lp;                            // logs
            }
            // next x = act @ W_embed + b_embed
            float v2 = bemb[t];
            #pragma unroll
            for (int j = 0; j < AD; j++)
                v2 += actv[j]*Wemb[j*DM + t];
            xls[t] = v2;
            __syncthreads();
        }
    }
}

// ---------------- launch ----------------

extern "C" void kernel_launch(void* const* d_in, const int* in_sizes, int n_in,
                              void* d_out, int out_size, void* d_ws, size_t ws_size,
                              hipStream_t stream)
{
    const float* in[29];
    for (int k = 0; k < 29; k++) in[k] = (const float*)d_in[k];

    // workspace layout (bytes), total ~93 MB
    char* wsb = (char*)d_ws;
    uint32*   W1u  = (uint32*)(wsb);                       // 16 MB
    uint32*   Wou  = (uint32*)(wsb + (16u<<20));           //  8 MB
    ushort16* Wxb  = (ushort16*)(wsb + (24u<<20));         //  1.5 MB
    ushort16* Wdtb = (ushort16*)(wsb + (26u<<20));         //  0.5 MB
    float*    negA = (float*)(wsb + (27u<<20));            //  1 MB
    float*    ctx  = (float*)(wsb + (28u<<20));            //  2 MB
    uint32*   hG   = (uint32*)(wsb + (30u<<20));           // 64 MB

    float* out = (float*)d_out;

    k_negA<<<dim3(1024),  256, 0, stream>>>(in[17], in[26], negA);
    k_ctx <<<dim3(B*NA),  256, 0, stream>>>(in[0], in[1], in[5], ctx);
    k_w1  <<<dim3(16384), 256, 0, stream>>>(in[11], in[20], W1u);
    k_wo  <<<dim3(8192),  256, 0, stream>>>(in[19], in[28], Wou);
    k_wx  <<<dim3(3072),  256, 0, stream>>>(in[14], in[23], Wxb);
    k_wdt <<<dim3(1024),  256, 0, stream>>>(in[15], in[24], Wdtb);

    k_main<<<dim3(B), TPB, 0, stream>>>(
        in[6], in[7], in[8], in[9], in[10], in[2], in[3], in[4],
        in[12], in[13], in[16], in[18],
        in[21], in[22], in[25], in[27],
        W1u, Wou, Wxb, Wdtb, negA, ctx, hG, out);
}

// Round 8
// 3067.544 us; speedup vs baseline: 3.8730x; 3.8730x over previous
//
#include <hip/hip_runtime.h>
#include <hip/hip_bf16.h>

#define B   128
#define NA  8
#define AD  16
#define DM  512
#define DI  1024
#define DS  32
#define DC  4
#define DR  32
#define NB  4
#define OD  128

typedef __hip_bfloat16 bf16;
typedef unsigned int uint32;
typedef unsigned short ushort16;

__device__ __forceinline__ float bf2f(bf16 h){ return __bfloat162float(h); }
__device__ __forceinline__ float sigmoidf_(float x){ return 1.0f/(1.0f+__expf(-x)); }
__device__ __forceinline__ float softplusf_(float x){ return fmaxf(x,0.0f)+log1pf(__expf(-fabsf(x))); }
__device__ __forceinline__ float lo2f(uint32 u){ return __uint_as_float(u<<16); }
__device__ __forceinline__ float hi2f(uint32 u){ return __uint_as_float(u & 0xffff0000u); }
__device__ __forceinline__ uint32 packbf2(float a, float b){
    bf16 ha = __float2bfloat16(a), hb = __float2bfloat16(b);
    ushort16 sa = *reinterpret_cast<ushort16*>(&ha);
    ushort16 sb = *reinterpret_cast<ushort16*>(&hb);
    return (uint32)sa | ((uint32)sb << 16);
}
__device__ __forceinline__ ushort16 f2us(float a){
    bf16 ha = __float2bfloat16(a);
    return *reinterpret_cast<ushort16*>(&ha);
}

// ---------------- init / conversion kernels ----------------

__global__ __launch_bounds__(256) void k_negA(const float* __restrict__ Als,
    const float* __restrict__ Alc, float* __restrict__ negA)
{
    int idx = blockIdx.x*256 + threadIdx.x;   // < 2*NB*DI*DS = 262144
    int bs = idx >> 15;
    int r  = idx & 32767;
    int nb = bs >> 1, st = bs & 1;
    const float* src = (st ? Alc : Als) + (size_t)nb*DI*DS + r;
    negA[idx] = -__expf(*src);
}

__global__ __launch_bounds__(256) void k_ctx(const float* __restrict__ obs_rep,
    const float* __restrict__ obs, const float* __restrict__ Wobs,
    float* __restrict__ ctx)
{
    int ib = blockIdx.x;          // < B*8
    int b = ib >> 3, i = ib & 7;
    __shared__ float orow[OD];
    int tid = threadIdx.x;
    if (tid < OD) orow[tid] = obs[(size_t)(b*NA+i)*OD + tid];
    __syncthreads();
    for (int m = tid; m < DM; m += 256){
        float acc = obs_rep[(size_t)(b*NA+i)*DM + m];
        for (int o = 0; o < OD; o++)
            acc += orow[o]*Wobs[o*DM + m];
        ctx[(size_t)(i*B + b)*DM + m] = acc;
    }
}

// W1b[bs][k][c] bf16, [8][512][2048] — straight cast of in_proj
__global__ __launch_bounds__(256) void k_w1(const float* __restrict__ Ws,
    const float* __restrict__ Wc, ushort16* __restrict__ W1b)
{
    int idx = blockIdx.x*256 + threadIdx.x;   // < 8*1048576
    int bs = idx >> 20;
    int r  = idx & 1048575;
    int nb = bs >> 1, st = bs & 1;
    const float* src = (st ? Wc : Ws) + (size_t)nb*1048576 + r;
    W1b[idx] = f2us(*src);
}

// WoU[bs][k][p] = packed pair (cols 2p,2p+1) of out_proj (1024 x 512)
__global__ __launch_bounds__(256) void k_wo(const float* __restrict__ Ws,
    const float* __restrict__ Wc, uint32* __restrict__ WoU)
{
    int idx = blockIdx.x*256 + threadIdx.x;   // < 8*262144
    int bs = idx >> 18;
    int r  = idx & 262143;
    int k  = r >> 8, p = r & 255;
    int nb = bs >> 1, st = bs & 1;
    const float* src = (st ? Wc : Ws) + (size_t)nb*DI*DM + (size_t)k*DM + 2*p;
    WoU[idx] = packbf2(src[0], src[1]);
}

// Wxb[bs][j][k] bf16 — TRANSPOSED x_proj: [8][96][1024]
__global__ __launch_bounds__(256) void k_wx(const float* __restrict__ Ws,
    const float* __restrict__ Wc, ushort16* __restrict__ Wxb)
{
    int idx = blockIdx.x*256 + threadIdx.x;   // < 8*98304
    int bs = idx / 98304;
    int r  = idx % 98304;
    int j  = r >> 10, k = r & 1023;
    int nb = bs >> 1, st = bs & 1;
    const float* src = (st ? Wc : Ws) + (size_t)nb*DI*96 + (size_t)k*96 + j;
    Wxb[idx] = f2us(*src);
}

// Wdtb[bs][r][d] bf16 [8][32][1024]
__global__ __launch_bounds__(256) void k_wdt(const float* __restrict__ Ws,
    const float* __restrict__ Wc, ushort16* __restrict__ Wdtb)
{
    int idx = blockIdx.x*256 + threadIdx.x;   // < 8*32768
    int bs = idx >> 15;
    int r  = idx & 32767;
    int nb = bs >> 1, st = bs & 1;
    const float* src = (st ? Wc : Ws) + (size_t)nb*DR*DI + r;
    Wdtb[idx] = f2us(*src);
}

// x0 = bemb broadcast; zero partials
__global__ __launch_bounds__(256) void k_init(const float* __restrict__ bemb,
    float* __restrict__ xb0, float* __restrict__ p0, float* __restrict__ p1)
{
    int idx = blockIdx.x*256 + threadIdx.x;   // < B*DM = 65536
    xb0[idx] = bemb[idx & (DM-1)];
    p0[idx] = 0.f;
    p1[idx] = 0.f;
}

// ---------------- per-step kernels (256 blocks = 128 rows x 2 halves) ----------------

// step1: fold x+p0+p1, LN(+ctx), gemm1 (N-half), conv ring + silu -> xc, sz
__global__ __launch_bounds__(512) void k_step1(
    const float* __restrict__ xin, const float* __restrict__ p0,
    const float* __restrict__ p1, float* __restrict__ xout,
    const float* __restrict__ lns, const float* __restrict__ ctxG,
    const bf16* __restrict__ W1b, const float* __restrict__ cw,
    const float* __restrict__ cb, uint32* __restrict__ convrU,
    float* __restrict__ xcG, float* __restrict__ szG, int i, int st, int bs)
{
    int row = blockIdx.x >> 1, hx = blockIdx.x & 1;
    int t = threadIdx.x, lane = t & 63, wid = t >> 6;
    __shared__ float ulnL[512];
    __shared__ float red1[4096];
    __shared__ float wps[8], wpq[8], ms2[2];

    float v = xin[(size_t)row*DM + t] + p0[(size_t)row*DM + t] + p1[(size_t)row*DM + t];
    if (hx == 0) xout[(size_t)row*DM + t] = v;
    float s = v, q = v*v;
    for (int off = 32; off > 0; off >>= 1){
        s += __shfl_down(s, off);
        q += __shfl_down(q, off);
    }
    if (lane == 0){ wps[wid] = s; wpq[wid] = q; }
    __syncthreads();
    if (t == 0){
        float S = 0.f, Q = 0.f;
        #pragma unroll
        for (int w2 = 0; w2 < 8; w2++){ S += wps[w2]; Q += wpq[w2]; }
        float m = S*(1.0f/DM);
        float var = Q*(1.0f/DM) - m*m;
        ms2[0] = m; ms2[1] = rsqrtf(var + 1e-5f);
    }
    __syncthreads();
    float u = (v - ms2[0])*ms2[1]*lns[t];
    if (st) u += ctxG[((size_t)i*B + row)*DM + t];
    ulnL[t] = u;
    __syncthreads();

    // gemm1: thread -> (K-group g of 128, window w (x/z), lane l) -> 8 cols
    int g = t >> 7, w = (t >> 6) & 1, l = t & 63;
    int col0 = w*1024 + hx*512 + 8*l;   // global col in [0,2048)
    const uint4* wp4 = (const uint4*)(W1b + ((size_t)bs << 20));
    float a0=0.f,a1=0.f,a2=0.f,a3=0.f,a4=0.f,a5=0.f,a6=0.f,a7=0.f;
    int kbeg = g*128;
    #pragma unroll 4
    for (int k = kbeg; k < kbeg + 128; k++){
        float a = ulnL[k];
        uint4 q4 = wp4[(size_t)k*256 + (col0 >> 3)];
        a0 += a*lo2f(q4.x); a1 += a*hi2f(q4.x);
        a2 += a*lo2f(q4.y); a3 += a*hi2f(q4.y);
        a4 += a*lo2f(q4.z); a5 += a*hi2f(q4.z);
        a6 += a*lo2f(q4.w); a7 += a*hi2f(q4.w);
    }
    int lbase = g*1024 + w*512 + 8*l;
    *(float4*)&red1[lbase]     = make_float4(a0,a1,a2,a3);
    *(float4*)&red1[lbase + 4] = make_float4(a4,a5,a6,a7);
    __syncthreads();

    int lc = 2*t;
    float xz0 = red1[lc]   + red1[1024+lc]   + red1[2048+lc]   + red1[3072+lc];
    float xz1 = red1[lc+1] + red1[1024+lc+1] + red1[2048+lc+1] + red1[3072+lc+1];
    if (t < 256){
        int d0 = hx*512 + lc;                 // lc < 512
        int pidx = hx*256 + t;
        uint32* ring = convrU + ((size_t)bs << 18);   // [4][128][512] uints
        ring[(((size_t)(i&3))*128 + row)*512 + pidx] = packbf2(xz0, xz1);
        float s0 = cb[d0]   + cw[3*DI + d0]  *xz0;
        float s1 = cb[d0+1] + cw[3*DI + d0+1]*xz1;
        if (i >= 1){ uint32 uu = ring[(((size_t)((i-1)&3))*128 + row)*512 + pidx];
            s0 += cw[2*DI + d0]*lo2f(uu); s1 += cw[2*DI + d0+1]*hi2f(uu); }
        if (i >= 2){ uint32 uu = ring[(((size_t)((i-2)&3))*128 + row)*512 + pidx];
            s0 += cw[1*DI + d0]*lo2f(uu); s1 += cw[1*DI + d0+1]*hi2f(uu); }
        if (i >= 3){ uint32 uu = ring[(((size_t)((i-3)&3))*128 + row)*512 + pidx];
            s0 += cw[0*DI + d0]*lo2f(uu); s1 += cw[0*DI + d0+1]*hi2f(uu); }
        xcG[(size_t)row*DI + d0]   = s0*sigmoidf_(s0);
        xcG[(size_t)row*DI + d0+1] = s1*sigmoidf_(s1);
    } else {
        int c = lc - 512;
        int d0 = hx*512 + c;
        szG[(size_t)row*DI + d0]   = xz0*sigmoidf_(xz0);
        szG[(size_t)row*DI + d0+1] = xz1*sigmoidf_(xz1);
    }
}

// step2: xproj (full xc, redundant per half), dt, h update (d-half), yz, gemm2 partial (K-half)
__global__ __launch_bounds__(512) void k_step2(
    const float* __restrict__ xcG, const float* __restrict__ szG,
    const bf16* __restrict__ Wxb, const bf16* __restrict__ Wdtb,
    const float* __restrict__ dtb, const float* __restrict__ Dp,
    const float* __restrict__ negA, const uint32* __restrict__ WoU,
    uint32* __restrict__ hG, float* __restrict__ p0, float* __restrict__ p1,
    int first, int bs)
{
    int row = blockIdx.x >> 1, hx = blockIdx.x & 1;
    int t = threadIdx.x;
    __shared__ float xcL[1024];
    __shared__ float partx[384];
    __shared__ float rowS[96];
    __shared__ float yzL[512];
    __shared__ float red2[2048];

    xcL[t]       = xcG[(size_t)row*DI + t];
    xcL[512 + t] = xcG[(size_t)row*DI + 512 + t];
    __syncthreads();

    if (t < 384){
        int sl = t / 96, j = t - sl*96;
        int k0 = sl*256;
        const uint4* wx4 = (const uint4*)(Wxb + (size_t)bs*98304 + (size_t)j*1024 + k0);
        float acc = 0.f;
        #pragma unroll 4
        for (int ii = 0; ii < 32; ii++){
            uint4 q4 = wx4[ii];
            int kk = k0 + 8*ii;
            acc += xcL[kk+0]*lo2f(q4.x) + xcL[kk+1]*hi2f(q4.x)
                 + xcL[kk+2]*lo2f(q4.y) + xcL[kk+3]*hi2f(q4.y)
                 + xcL[kk+4]*lo2f(q4.z) + xcL[kk+5]*hi2f(q4.z)
                 + xcL[kk+6]*lo2f(q4.w) + xcL[kk+7]*hi2f(q4.w);
        }
        partx[t] = acc;
    }
    __syncthreads();
    if (t < 96) rowS[t] = partx[t] + partx[t+96] + partx[t+192] + partx[t+288];
    __syncthreads();

    {
        int d = hx*512 + t;
        float dp = dtb[d];
        const bf16* wdt = Wdtb + ((size_t)bs << 15);
        #pragma unroll 8
        for (int r = 0; r < DR; r++)
            dp += rowS[r]*bf2f(wdt[(size_t)r*DI + d]);
        float delta = softplusf_(dp);
        float xcv = xcL[d];
        float dxc = delta*xcv;
        const float4* nap = (const float4*)(negA + ((size_t)bs << 15) + (size_t)d*DS);
        uint4* hp = (uint4*)(hG + (((size_t)bs*B + row)*DI + d)*16);
        float y = 0.f;
        #pragma unroll
        for (int qq = 0; qq < 4; qq++){
            uint4 hu = first ? make_uint4(0u,0u,0u,0u) : hp[qq];
            float4 na0 = nap[2*qq], na1 = nap[2*qq+1];
            int s0 = 8*qq;
            float h0 = lo2f(hu.x), h1 = hi2f(hu.x);
            float h2 = lo2f(hu.y), h3 = hi2f(hu.y);
            float h4 = lo2f(hu.z), h5 = hi2f(hu.z);
            float h6 = lo2f(hu.w), h7 = hi2f(hu.w);
            h0 = __expf(delta*na0.x)*h0 + dxc*rowS[DR+s0+0];
            h1 = __expf(delta*na0.y)*h1 + dxc*rowS[DR+s0+1];
            h2 = __expf(delta*na0.z)*h2 + dxc*rowS[DR+s0+2];
            h3 = __expf(delta*na0.w)*h3 + dxc*rowS[DR+s0+3];
            h4 = __expf(delta*na1.x)*h4 + dxc*rowS[DR+s0+4];
            h5 = __expf(delta*na1.y)*h5 + dxc*rowS[DR+s0+5];
            h6 = __expf(delta*na1.z)*h6 + dxc*rowS[DR+s0+6];
            h7 = __expf(delta*na1.w)*h7 + dxc*rowS[DR+s0+7];
            y += h0*rowS[DR+DS+s0+0] + h1*rowS[DR+DS+s0+1]
               + h2*rowS[DR+DS+s0+2] + h3*rowS[DR+DS+s0+3]
               + h4*rowS[DR+DS+s0+4] + h5*rowS[DR+DS+s0+5]
               + h6*rowS[DR+DS+s0+6] + h7*rowS[DR+DS+s0+7];
            hu.x = packbf2(h0,h1); hu.y = packbf2(h2,h3);
            hu.z = packbf2(h4,h5); hu.w = packbf2(h6,h7);
            hp[qq] = hu;
        }
        y += Dp[d]*xcv;
        yzL[t] = y*szG[(size_t)row*DI + d];
    }
    __syncthreads();

    // gemm2 partial: K-half = yzL[0..511] at global k = hx*512+..., all 512 cols
    {
        int kg = t >> 7, c = t & 127;
        const uint2* wo2 = (const uint2*)(WoU + ((size_t)bs << 18));
        float b0=0.f,b1=0.f,b2=0.f,b3=0.f;
        int kb = kg*128;
        #pragma unroll 4
        for (int kk = 0; kk < 128; kk++){
            int kl = kb + kk;
            float av = yzL[kl];
            uint2 u2 = wo2[(size_t)(hx*512 + kl)*128 + c];
            b0 += av*lo2f(u2.x); b1 += av*hi2f(u2.x);
            b2 += av*lo2f(u2.y); b3 += av*hi2f(u2.y);
        }
        *(float4*)&red2[kg*512 + 4*c] = make_float4(b0,b1,b2,b3);
    }
    __syncthreads();
    {
        float pv = red2[t] + red2[512+t] + red2[1024+t] + red2[1536+t];
        float* pO = hx ? p1 : p0;
        pO[(size_t)row*DM + t] = pv;
    }
}

// head: fold, LN, W_head GEMV, outputs, next x = act@Wemb + bemb, zero partials
__global__ __launch_bounds__(512) void k_head(
    const float* __restrict__ xin, float* __restrict__ xout,
    float* __restrict__ p0, float* __restrict__ p1,
    const float* __restrict__ lno, const float* __restrict__ Whead,
    const float* __restrict__ logstd, const float* __restrict__ eps,
    const float* __restrict__ Wemb, const float* __restrict__ bemb,
    float* __restrict__ out, int agent)
{
    int b = blockIdx.x, t = threadIdx.x, lane = t & 63, wid = t >> 6;
    __shared__ float ulnL[512];
    __shared__ float redH[512];
    __shared__ float wps[8], wpq[8], ms2[2];
    __shared__ float actv[AD], lpterm[AD];

    float v = xin[(size_t)b*DM + t] + p0[(size_t)b*DM + t] + p1[(size_t)b*DM + t];
    float s = v, q = v*v;
    for (int off = 32; off > 0; off >>= 1){
        s += __shfl_down(s, off);
        q += __shfl_down(q, off);
    }
    if (lane == 0){ wps[wid] = s; wpq[wid] = q; }
    __syncthreads();
    if (t == 0){
        float S = 0.f, Q = 0.f;
        #pragma unroll
        for (int w2 = 0; w2 < 8; w2++){ S += wps[w2]; Q += wpq[w2]; }
        float m = S*(1.0f/DM);
        float var = Q*(1.0f/DM) - m*m;
        ms2[0] = m; ms2[1] = rsqrtf(var + 1e-5f);
    }
    __syncthreads();
    ulnL[t] = (v - ms2[0])*ms2[1]*lno[t];
    __syncthreads();
    {
        int ks = t >> 4, j = t & 15;
        float acc = 0.f;
        int k0 = ks*16;
        #pragma unroll
        for (int k = k0; k < k0 + 16; k++)
            acc += ulnL[k]*Whead[k*AD + j];
        redH[t] = acc;
    }
    __syncthreads();
    if (t < AD){
        int j = t;
        float mean = 0.f;
        #pragma unroll
        for (int ks = 0; ks < 32; ks++) mean += redH[ks*16 + j];
        float stdj = softplusf_(logstd[j]);
        float e = eps[((size_t)b*NA + agent)*AD + j];
        float raw = mean + stdj*e;
        float act = tanhf(raw);
        out[((size_t)b*NA + agent)*AD + j] = act;                                    // acts
        out[(size_t)NA*B*AD + (size_t)B*NA + ((size_t)b*NA + agent)*AD + j] = raw;   // raws
        actv[j] = act;
        lpterm[j] = -0.5f*e*e - logf(stdj)
                    - 2.0f*(0.69314718f - raw - softplusf_(-2.0f*raw));
    }
    __syncthreads();
    if (t == 0){
        float lp = 0.f;
        #pragma unroll
        for (int j = 0; j < AD; j++) lp += lpterm[j];
        lp -= 0.5f*AD*1.8378770664f;
        out[(size_t)NA*B*AD + (size_t)b*NA + agent] = lp;                            // logs
    }
    float v2 = bemb[t];
    #pragma unroll
    for (int j = 0; j < AD; j++)
        v2 += actv[j]*Wemb[j*DM + t];
    xout[(size_t)b*DM + t] = v2;
    p0[(size_t)b*DM + t] = 0.f;
    p1[(size_t)b*DM + t] = 0.f;
}

// ---------------- launch ----------------

extern "C" void kernel_launch(void* const* d_in, const int* in_sizes, int n_in,
                              void* d_out, int out_size, void* d_ws, size_t ws_size,
                              hipStream_t stream)
{
    const float* in[29];
    for (int k = 0; k < 29; k++) in[k] = (const float*)d_in[k];

    // workspace layout (bytes), total ~103 MB (ws >= ~110 MB evidenced by round 3/4)
    char* wsb = (char*)d_ws;
    bf16*   W1b  = (bf16*)  (wsb + 0);           // 16,777,216
    uint32* WoU  = (uint32*)(wsb + 16777216);    //  8,388,608
    bf16*   Wxb  = (bf16*)  (wsb + 25165824);    //  1,572,864
    bf16*   Wdtb = (bf16*)  (wsb + 26738688);    //    524,288
    float*  negA = (float*) (wsb + 27262976);    //  1,048,576
    float*  ctx  = (float*) (wsb + 28311552);    //  2,097,152
    float*  xb0  = (float*) (wsb + 30408704);    //    262,144
    float*  xb1  = (float*) (wsb + 30670848);    //    262,144
    float*  p0   = (float*) (wsb + 30932992);    //    262,144
    float*  p1   = (float*) (wsb + 31195136);    //    262,144
    float*  xcG  = (float*) (wsb + 31457280);    //    524,288
    float*  szG  = (float*) (wsb + 31981568);    //    524,288
    uint32* convrU = (uint32*)(wsb + 32505856);  //  8,388,608
    uint32* hG   = (uint32*)(wsb + 40894464);    // 67,108,864  (end 108,003,328)

    float* out = (float*)d_out;
    float* xb[2] = {xb0, xb1};

    k_negA<<<dim3(1024),  256, 0, stream>>>(in[17], in[26], negA);
    k_ctx <<<dim3(B*NA),  256, 0, stream>>>(in[0], in[1], in[5], ctx);
    k_w1  <<<dim3(32768), 256, 0, stream>>>(in[11], in[20], (ushort16*)W1b);
    k_wo  <<<dim3(8192),  256, 0, stream>>>(in[19], in[28], WoU);
    k_wx  <<<dim3(3072),  256, 0, stream>>>(in[14], in[23], (ushort16*)Wxb);
    k_wdt <<<dim3(1024),  256, 0, stream>>>(in[15], in[24], (ushort16*)Wdtb);
    k_init<<<dim3(256),   256, 0, stream>>>(in[4], xb0, p0, p1);

    int cur = 0;
    for (int i = 0; i < NA; i++){
        for (int nb = 0; nb < NB; nb++){
            for (int st = 0; st < 2; st++){
                int bs = nb*2 + st;
                int base = st ? 20 : 11;
                const float* cw   = in[base+1] + (size_t)nb*DC*DI;
                const float* cb   = in[base+2] + (size_t)nb*DI;
                const float* dtbp = in[base+5] + (size_t)nb*DI;
                const float* Dpp  = in[base+7] + (size_t)nb*DI;
                const float* lns  = (st ? in[7] : in[6]) + (size_t)nb*DM;

                k_step1<<<dim3(256), 512, 0, stream>>>(xb[cur], p0, p1, xb[cur^1],
                        lns, ctx, W1b, cw, cb, convrU, xcG, szG, i, st, bs);
                cur ^= 1;
                k_step2<<<dim3(256), 512, 0, stream>>>(xcG, szG, Wxb, Wdtb,
                        dtbp, Dpp, negA, WoU, hG, p0, p1, (i==0) ? 1 : 0, bs);
            }
        }
        k_head<<<dim3(B), 512, 0, stream>>>(xb[cur], xb[cur^1], p0, p1,
                in[8], in[9], in[10], in[2], in[3], in[4], out, i);
        cur ^= 1;
    }
}